// Round 1
// baseline (2997.544 us; speedup 1.0000x reference)
//
#include <hip/hip_runtime.h>
#include <hip/hip_bf16.h>

#define HIDDEN 1024
#define INTER  2048
#define NEXP   8

#define TM 64
#define TN 64
#define TK 16

// hdr layout (ints at start of workspace):
// [0..7]  = cnt2      (tokens routed to expert e via top-2)
// [8..15] = cnt1      (top-1 counts, for aux loss)
// [16..23]= cursor    (scatter cursors)
// [24..31]= seg_base  (row offset of expert e's segment, TM-aligned)
// [32..39]= seg_cap   (padded capacity of segment)
// [40]    = rows_total

__device__ __forceinline__ unsigned short f2bf(float f) {
    __hip_bfloat16 h = __float2bfloat16(f);
    return *reinterpret_cast<unsigned short*>(&h);
}
__device__ __forceinline__ float bf2f(unsigned short u) {
    return __uint_as_float(((unsigned int)u) << 16);
}

// ---------------- Router: fp64 logits -> softmax -> top2 + aux accumulators ----
__global__ __launch_bounds__(64) void router_kernel(
    const float* __restrict__ x, const float* __restrict__ wr,
    int* __restrict__ top_e, float* __restrict__ top_w,
    int* __restrict__ hdr, double* __restrict__ probs_sum)
{
    int tok = blockIdx.x;
    int lane = threadIdx.x;
    const float* xr = x + (size_t)tok * HIDDEN;
    double acc[NEXP];
#pragma unroll
    for (int e = 0; e < NEXP; e++) acc[e] = 0.0;
    for (int h = lane; h < HIDDEN; h += 64) {
        float xv = xr[h];
        const float* w = wr + h * NEXP;
#pragma unroll
        for (int e = 0; e < NEXP; e++) acc[e] += (double)xv * (double)w[e];
    }
#pragma unroll
    for (int e = 0; e < NEXP; e++) {
        double v = acc[e];
#pragma unroll
        for (int off = 32; off > 0; off >>= 1) v += __shfl_down(v, off);
        acc[e] = v;
    }
    if (lane == 0) {
        double mx = acc[0];
#pragma unroll
        for (int e = 1; e < NEXP; e++) mx = fmax(mx, acc[e]);
        double p[NEXP], s = 0.0;
#pragma unroll
        for (int e = 0; e < NEXP; e++) { p[e] = exp(acc[e] - mx); s += p[e]; }
#pragma unroll
        for (int e = 0; e < NEXP; e++) p[e] /= s;
        // top-1 (strict > keeps lowest index on ties, matching lax.top_k)
        int e0 = 0;
#pragma unroll
        for (int e = 1; e < NEXP; e++) if (p[e] > p[e0]) e0 = e;
        int e1 = (e0 == 0) ? 1 : 0;
#pragma unroll
        for (int e = 0; e < NEXP; e++) if (e != e0 && p[e] > p[e1]) e1 = e;
        double sw = p[e0] + p[e1];
        top_e[tok * 2 + 0] = e0;
        top_e[tok * 2 + 1] = e1;
        top_w[tok * 2 + 0] = (float)(p[e0] / sw);
        top_w[tok * 2 + 1] = (float)(p[e1] / sw);
        atomicAdd(&hdr[8 + e0], 1);   // cnt1
        atomicAdd(&hdr[0 + e0], 1);   // cnt2
        atomicAdd(&hdr[0 + e1], 1);
#pragma unroll
        for (int e = 0; e < NEXP; e++)
            __hip_atomic_fetch_add(&probs_sum[e], p[e], __ATOMIC_RELAXED,
                                   __HIP_MEMORY_SCOPE_AGENT);
    }
}

// ---------------- Segment setup + aux loss ------------------------------------
__global__ void setup_kernel(int* __restrict__ hdr,
                             const double* __restrict__ probs_sum,
                             float* __restrict__ aux_out, int n)
{
    if (threadIdx.x == 0 && blockIdx.x == 0) {
        int off = 0;
        for (int e = 0; e < NEXP; e++) {
            hdr[24 + e] = off;
            int cap = (hdr[e] + TM - 1) / TM * TM;
            hdr[32 + e] = cap;
            off += cap;
        }
        hdr[40] = off;
        double aux = 0.0;
        for (int e = 0; e < NEXP; e++)
            aux += ((double)hdr[8 + e] / (double)n) * (probs_sum[e] / (double)n);
        *aux_out = (float)(aux * NEXP);
    }
}

// ---------------- Scatter tokens into per-expert row lists --------------------
__global__ __launch_bounds__(256) void scatter_kernel(
    const int* __restrict__ top_e, const float* __restrict__ top_w,
    int* __restrict__ hdr, int* __restrict__ row_tok, float* __restrict__ row_w,
    int n)
{
    int t = blockIdx.x * 256 + threadIdx.x;
    if (t >= n) return;
#pragma unroll
    for (int k = 0; k < 2; k++) {
        int e = top_e[t * 2 + k];
        int pos = atomicAdd(&hdr[16 + e], 1);
        int row = hdr[24 + e] + pos;
        row_tok[row] = t;
        row_w[row] = top_w[t * 2 + k];
    }
}

// ---------------- expert lookup helper ----------------------------------------
__device__ __forceinline__ int find_expert(const int* hdr, int row0, bool* skip)
{
    int e = -1;
#pragma unroll
    for (int i = 0; i < NEXP; i++) {
        int sb = hdr[24 + i];
        if (row0 >= sb && row0 < sb + hdr[32 + i]) e = i;
    }
    *skip = true;
    if (e < 0) return -1;
    if (row0 - hdr[24 + e] >= hdr[e]) return -1;  // tile entirely padding
    *skip = false;
    return e;
}

// ---------------- GEMM1: H = silu(X_gathered @ W1[e]) -> bf16 -----------------
__global__ __launch_bounds__(256) void gemm1_kernel(
    const float* __restrict__ x, const float* __restrict__ w1,
    const int* __restrict__ hdr, const int* __restrict__ row_tok,
    unsigned short* __restrict__ Hbuf)
{
    __shared__ __align__(16) float As[TK][TM];
    __shared__ __align__(16) float Bs[TK][TN];

    int row0 = blockIdx.x * TM;
    bool skip;
    int e = find_expert(hdr, row0, &skip);
    if (skip) return;

    int n0 = blockIdx.y * TN;
    int tid = threadIdx.x;

    int a_row = tid >> 2;          // 0..63
    int a_kq  = tid & 3;           // k-offset = a_kq*4
    int tok = row_tok[row0 + a_row];
    const float* a_src = (tok >= 0) ? (x + (size_t)tok * HIDDEN + a_kq * 4) : nullptr;

    int b_k  = tid >> 4;           // 0..15
    int b_nq = tid & 15;           // col offset = b_nq*4
    const float* b_src = w1 + (size_t)e * HIDDEN * INTER + (size_t)b_k * INTER
                            + n0 + b_nq * 4;

    int ty = tid >> 4;
    int tx = tid & 15;
    float acc[4][4] = {};

    for (int k0 = 0; k0 < HIDDEN; k0 += TK) {
        float4 av = a_src ? *(const float4*)(a_src + k0) : float4{0.f, 0.f, 0.f, 0.f};
        float4 bv = *(const float4*)(b_src + (size_t)k0 * INTER);
        __syncthreads();
        As[a_kq * 4 + 0][a_row] = av.x;
        As[a_kq * 4 + 1][a_row] = av.y;
        As[a_kq * 4 + 2][a_row] = av.z;
        As[a_kq * 4 + 3][a_row] = av.w;
        *(float4*)&Bs[b_k][b_nq * 4] = bv;
        __syncthreads();
#pragma unroll
        for (int k = 0; k < TK; k++) {
            float4 a = *(const float4*)&As[k][ty * 4];
            float4 b = *(const float4*)&Bs[k][tx * 4];
            float ar[4] = {a.x, a.y, a.z, a.w};
            float br[4] = {b.x, b.y, b.z, b.w};
#pragma unroll
            for (int i = 0; i < 4; i++)
#pragma unroll
                for (int j = 0; j < 4; j++) acc[i][j] += ar[i] * br[j];
        }
    }

#pragma unroll
    for (int i = 0; i < 4; i++) {
        int row = row0 + ty * 4 + i;
        size_t base = (size_t)row * INTER + n0 + tx * 4;
        ushort4 pk;
        float v0 = acc[i][0], v1 = acc[i][1], v2 = acc[i][2], v3 = acc[i][3];
        pk.x = f2bf(v0 / (1.0f + __expf(-v0)));
        pk.y = f2bf(v1 / (1.0f + __expf(-v1)));
        pk.z = f2bf(v2 / (1.0f + __expf(-v2)));
        pk.w = f2bf(v3 / (1.0f + __expf(-v3)));
        *(ushort4*)&Hbuf[base] = pk;
    }
}

// ---------------- GEMM2: out[tok] += w * (H @ W2[e]) --------------------------
__global__ __launch_bounds__(256) void gemm2_kernel(
    const unsigned short* __restrict__ Hbuf, const float* __restrict__ w2,
    const int* __restrict__ hdr, const int* __restrict__ row_tok,
    const float* __restrict__ row_w, float* __restrict__ out)
{
    __shared__ __align__(16) float As[TK][TM];
    __shared__ __align__(16) float Bs[TK][TN];

    int row0 = blockIdx.x * TM;
    bool skip;
    int e = find_expert(hdr, row0, &skip);
    if (skip) return;

    int n0 = blockIdx.y * TN;
    int tid = threadIdx.x;

    int a_row = tid >> 2;
    int a_kq  = tid & 3;
    const unsigned short* a_src = Hbuf + (size_t)(row0 + a_row) * INTER + a_kq * 4;

    int b_k  = tid >> 4;
    int b_nq = tid & 15;
    const float* b_src = w2 + (size_t)e * INTER * HIDDEN + (size_t)b_k * HIDDEN
                            + n0 + b_nq * 4;

    int ty = tid >> 4;
    int tx = tid & 15;
    float acc[4][4] = {};

    for (int k0 = 0; k0 < INTER; k0 += TK) {
        ushort4 a16 = *(const ushort4*)(a_src + k0);
        float4 bv = *(const float4*)(b_src + (size_t)k0 * HIDDEN);
        __syncthreads();
        As[a_kq * 4 + 0][a_row] = bf2f(a16.x);
        As[a_kq * 4 + 1][a_row] = bf2f(a16.y);
        As[a_kq * 4 + 2][a_row] = bf2f(a16.z);
        As[a_kq * 4 + 3][a_row] = bf2f(a16.w);
        *(float4*)&Bs[b_k][b_nq * 4] = bv;
        __syncthreads();
#pragma unroll
        for (int k = 0; k < TK; k++) {
            float4 a = *(const float4*)&As[k][ty * 4];
            float4 b = *(const float4*)&Bs[k][tx * 4];
            float ar[4] = {a.x, a.y, a.z, a.w};
            float br[4] = {b.x, b.y, b.z, b.w};
#pragma unroll
            for (int i = 0; i < 4; i++)
#pragma unroll
                for (int j = 0; j < 4; j++) acc[i][j] += ar[i] * br[j];
        }
    }

    int   tokv[4];
    float wv[4];
#pragma unroll
    for (int i = 0; i < 4; i++) {
        int row = row0 + ty * 4 + i;
        tokv[i] = row_tok[row];
        wv[i]   = row_w[row];
    }
#pragma unroll
    for (int i = 0; i < 4; i++) {
        if (tokv[i] < 0) continue;
        float* dst = out + (size_t)tokv[i] * HIDDEN + n0 + tx * 4;
#pragma unroll
        for (int j = 0; j < 4; j++)
            __hip_atomic_fetch_add(&dst[j], wv[i] * acc[i][j], __ATOMIC_RELAXED,
                                   __HIP_MEMORY_SCOPE_AGENT);
    }
}

// ---------------- Launch ------------------------------------------------------
extern "C" void kernel_launch(void* const* d_in, const int* in_sizes, int n_in,
                              void* d_out, int out_size, void* d_ws, size_t ws_size,
                              hipStream_t stream)
{
    const float* x  = (const float*)d_in[0];
    const float* wr = (const float*)d_in[1];
    const float* w1 = (const float*)d_in[2];
    const float* w2 = (const float*)d_in[3];
    float* out = (float*)d_out;

    int n = in_sizes[0] / HIDDEN;  // 8192 tokens

    // workspace layout
    int rowcap = ((2 * n + NEXP * (TM - 1)) + TM - 1) / TM * TM;  // 16896 for n=8192
    char* ws = (char*)d_ws;
    int*    hdr       = (int*)ws;                       // 256 B
    double* probs_sum = (double*)(ws + 256);            // 64 B
    size_t  off = 512;
    int*    row_tok = (int*)(ws + off);   off += (size_t)rowcap * 4;
    float*  row_w   = (float*)(ws + off); off += (size_t)rowcap * 4;
    int*    top_e   = (int*)(ws + off);   off += (size_t)n * 2 * 4;
    float*  top_w   = (float*)(ws + off); off += (size_t)n * 2 * 4;
    off = (off + 255) & ~(size_t)255;
    unsigned short* Hbuf = (unsigned short*)(ws + off); // rowcap * INTER bf16

    hipMemsetAsync(ws, 0, 512, stream);                              // counters
    hipMemsetAsync(row_tok, 0xFF, (size_t)rowcap * 4, stream);       // tok = -1
    hipMemsetAsync(out, 0, (size_t)out_size * 4, stream);            // accum out

    router_kernel<<<n, 64, 0, stream>>>(x, wr, top_e, top_w, hdr, probs_sum);
    setup_kernel<<<1, 64, 0, stream>>>(hdr, probs_sum, out + (out_size - 1), n);
    scatter_kernel<<<(n + 255) / 256, 256, 0, stream>>>(top_e, top_w, hdr,
                                                        row_tok, row_w, n);
    dim3 g1(rowcap / TM, INTER / TN);
    gemm1_kernel<<<g1, 256, 0, stream>>>(x, w1, hdr, row_tok, Hbuf);
    dim3 g2(rowcap / TM, HIDDEN / TN);
    gemm2_kernel<<<g2, 256, 0, stream>>>(Hbuf, w2, hdr, row_tok, row_w, out);
}

// Round 2
// 839.756 us; speedup vs baseline: 3.5695x; 3.5695x over previous
//
#include <hip/hip_runtime.h>
#include <hip/hip_bf16.h>

#define HIDDEN 1024
#define INTER  2048
#define NEXP   8
#define BM 128
#define BN 128
#define BK 32

typedef __bf16 bf16_t;
typedef __bf16 bf16x4 __attribute__((ext_vector_type(4)));
typedef __bf16 bf16x8 __attribute__((ext_vector_type(8)));
typedef float  f32x4  __attribute__((ext_vector_type(4)));

// async 16B global->LDS (DMA, no VGPR round-trip). LDS dest must be
// wave-uniform base + lane*16 — our chunk mapping guarantees it.
__device__ __forceinline__ void async_cp16(const bf16_t* g, bf16_t* l) {
    __builtin_amdgcn_global_load_lds(
        (const __attribute__((address_space(1))) unsigned int*)g,
        (__attribute__((address_space(3))) unsigned int*)l, 16, 0, 0);
}

// hdr: [0..7]=cnt2 [8..15]=cnt1 [16..23]=cursor [24..31]=seg_base [32..39]=seg_cap

// ---------------- Router: fp64 logits/softmax/top2 (selection-critical) -------
__global__ __launch_bounds__(256) void router_kernel(
    const float* __restrict__ x, const float* __restrict__ wr,
    int* __restrict__ top_e, float* __restrict__ top_w,
    int* __restrict__ hdr, float* __restrict__ probs_sum)
{
    __shared__ float psum[NEXP];
    int tid = threadIdx.x;
    if (tid < NEXP) psum[tid] = 0.f;
    __syncthreads();
    int lane = tid & 63;
    int tok = blockIdx.x * 4 + (tid >> 6);
    const float* xr = x + (size_t)tok * HIDDEN;
    double acc[NEXP];
#pragma unroll
    for (int e = 0; e < NEXP; e++) acc[e] = 0.0;
    for (int h = lane; h < HIDDEN; h += 64) {
        double xv = (double)xr[h];
        const float* w = wr + h * NEXP;
#pragma unroll
        for (int e = 0; e < NEXP; e++) acc[e] += xv * (double)w[e];
    }
#pragma unroll
    for (int e = 0; e < NEXP; e++) {
        double v = acc[e];
#pragma unroll
        for (int off = 32; off > 0; off >>= 1) v += __shfl_down(v, off);
        acc[e] = v;
    }
    if (lane == 0) {
        double mx = acc[0];
#pragma unroll
        for (int e = 1; e < NEXP; e++) mx = fmax(mx, acc[e]);
        double p[NEXP], s = 0.0;
#pragma unroll
        for (int e = 0; e < NEXP; e++) { p[e] = exp(acc[e] - mx); s += p[e]; }
#pragma unroll
        for (int e = 0; e < NEXP; e++) p[e] /= s;
        int e0 = 0;
#pragma unroll
        for (int e = 1; e < NEXP; e++) if (p[e] > p[e0]) e0 = e;
        int e1 = (e0 == 0) ? 1 : 0;
#pragma unroll
        for (int e = 0; e < NEXP; e++) if (e != e0 && p[e] > p[e1]) e1 = e;
        double sw = p[e0] + p[e1];
        top_e[tok * 2 + 0] = e0;
        top_e[tok * 2 + 1] = e1;
        top_w[tok * 2 + 0] = (float)(p[e0] / sw);
        top_w[tok * 2 + 1] = (float)(p[e1] / sw);
        atomicAdd(&hdr[8 + e0], 1);
        atomicAdd(&hdr[0 + e0], 1);
        atomicAdd(&hdr[0 + e1], 1);
#pragma unroll
        for (int e = 0; e < NEXP; e++) atomicAdd(&psum[e], (float)p[e]);
    }
    __syncthreads();
    if (tid < NEXP) atomicAdd(&probs_sum[tid], psum[tid]);
}

// ---------------- Segment setup + aux loss ------------------------------------
__global__ void setup_kernel(int* __restrict__ hdr,
                             const float* __restrict__ probs_sum,
                             float* __restrict__ aux_out, int n)
{
    if (threadIdx.x == 0 && blockIdx.x == 0) {
        int off = 0;
        for (int e = 0; e < NEXP; e++) {
            hdr[24 + e] = off;
            int cap = (hdr[e] + BM - 1) / BM * BM;
            hdr[32 + e] = cap;
            off += cap;
        }
        double aux = 0.0;
        for (int e = 0; e < NEXP; e++)
            aux += ((double)hdr[8 + e] / n) * ((double)probs_sum[e] / n);
        *aux_out = (float)(aux * NEXP);
    }
}

// ---------------- Scatter: token -> expert-segment rows -----------------------
__global__ __launch_bounds__(256) void scatter_kernel(
    const int* __restrict__ top_e, int* __restrict__ hdr,
    int* __restrict__ row_tok, int* __restrict__ row_of, int n)
{
    int t = blockIdx.x * 256 + threadIdx.x;
    if (t >= n) return;
#pragma unroll
    for (int k = 0; k < 2; k++) {
        int e = top_e[t * 2 + k];
        int pos = atomicAdd(&hdr[16 + e], 1);
        int row = hdr[24 + e] + pos;
        row_tok[row] = t;
        row_of[t * 2 + k] = row;
    }
}

// ---------------- x fp32 -> bf16 ----------------------------------------------
__global__ __launch_bounds__(256) void cvt_x_kernel(
    const float* __restrict__ x, bf16_t* __restrict__ xbf)
{
    int i = (blockIdx.x * 256 + threadIdx.x) * 4;
    float4 v = *(const float4*)(x + i);
    bf16x4 o = { (bf16_t)v.x, (bf16_t)v.y, (bf16_t)v.z, (bf16_t)v.w };
    *(bf16x4*)(xbf + i) = o;
}

// ---------------- per-expert transpose-convert [R][C]f32 -> [C][R]bf16 --------
__global__ __launch_bounds__(256) void transpose_cvt_kernel(
    const float* __restrict__ src, bf16_t* __restrict__ dst, int R, int C)
{
    __shared__ float tile[32][33];
    int e = blockIdx.z;
    int r0 = blockIdx.y * 32, c0 = blockIdx.x * 32;
    int tid = threadIdx.x;
    int r = tid >> 3, cq = (tid & 7) * 4;
    const float* s = src + ((size_t)e * R + r0 + r) * C + c0 + cq;
    float4 v = *(const float4*)s;
    tile[r][cq + 0] = v.x; tile[r][cq + 1] = v.y;
    tile[r][cq + 2] = v.z; tile[r][cq + 3] = v.w;
    __syncthreads();
    int c = tid >> 3, rq = (tid & 7) * 4;
    bf16x4 o = { (bf16_t)tile[rq + 0][c], (bf16_t)tile[rq + 1][c],
                 (bf16_t)tile[rq + 2][c], (bf16_t)tile[rq + 3][c] };
    *(bf16x4*)(dst + ((size_t)e * C + c0 + c) * R + r0 + rq) = o;
}

// ---------------- expert lookup ----------------------------------------------
__device__ __forceinline__ int tile_expert(const int* hdr, int row0)
{
    int e = -1;
#pragma unroll
    for (int i = 0; i < NEXP; i++) {
        int sb = hdr[24 + i];
        if (row0 >= sb && row0 < sb + hdr[32 + i]) e = i;
    }
    if (e >= 0 && row0 - hdr[24 + e] >= hdr[e]) e = -1;  // tile fully padding
    return e;
}

// ---------------- GEMM1: Hbuf = silu(X[rows] @ W1[e]) bf16 MFMA ---------------
__global__ __launch_bounds__(256) void gemm1_kernel(
    const bf16_t* __restrict__ xbf, const bf16_t* __restrict__ w1t,
    const int* __restrict__ hdr, const int* __restrict__ row_tok,
    bf16_t* __restrict__ Hbuf)
{
    __shared__ __align__(16) bf16_t As[BM * BK];
    __shared__ __align__(16) bf16_t Bs[BN * BK];

    int row0 = blockIdx.x * BM;
    int e = tile_expert(hdr, row0);
    if (e < 0) return;
    int n0 = blockIdx.y * BN;
    int tid = threadIdx.x;

    // staging chunk c (=tid, tid+256): LDS slot c*16B; row=c>>2, slot=c&3,
    // fetched k-chunk = slot ^ (row&3)  (XOR swizzle vs bank conflicts)
    int ar0 = tid >> 2, as0 = tid & 3, ak0 = as0 ^ (ar0 & 3);
    int ar1 = ar0 + 64, ak1 = as0 ^ (ar1 & 3);
    int t0 = row_tok[row0 + ar0]; if (t0 < 0) t0 = 0;
    int t1 = row_tok[row0 + ar1]; if (t1 < 0) t1 = 0;
    const bf16_t* ag0 = xbf + (size_t)t0 * HIDDEN + ak0 * 8;
    const bf16_t* ag1 = xbf + (size_t)t1 * HIDDEN + ak1 * 8;
    bf16_t* al0 = As + tid * 8;
    bf16_t* al1 = As + (tid + 256) * 8;

    const bf16_t* wb = w1t + (size_t)e * HIDDEN * INTER;  // [n][k]
    const bf16_t* bg0 = wb + (size_t)(n0 + ar0) * HIDDEN + ak0 * 8;
    const bf16_t* bg1 = wb + (size_t)(n0 + ar1) * HIDDEN + ak1 * 8;
    bf16_t* bl0 = Bs + tid * 8;
    bf16_t* bl1 = Bs + (tid + 256) * 8;

    int wave = tid >> 6, lane = tid & 63;
    int wm = (wave >> 1) * 64, wn = (wave & 1) * 64;
    int lrow = lane & 15, q = lane >> 4;

    int aoff[4], boff[4];
#pragma unroll
    for (int i = 0; i < 4; i++) {
        int r = wm + i * 16 + lrow;
        aoff[i] = r * BK + (q ^ (r & 3)) * 8;
        int s = wn + i * 16 + lrow;
        boff[i] = s * BK + (q ^ (s & 3)) * 8;
    }

    f32x4 acc[4][4] = {};

    for (int k0 = 0; k0 < HIDDEN; k0 += BK) {
        async_cp16(ag0 + k0, al0);
        async_cp16(ag1 + k0, al1);
        async_cp16(bg0 + k0, bl0);
        async_cp16(bg1 + k0, bl1);
        __syncthreads();   // drains vmcnt (async copies) before use
        bf16x8 af[4], bfr[4];
#pragma unroll
        for (int i = 0; i < 4; i++) {
            af[i]  = *(const bf16x8*)(As + aoff[i]);
            bfr[i] = *(const bf16x8*)(Bs + boff[i]);
        }
#pragma unroll
        for (int mi = 0; mi < 4; mi++)
#pragma unroll
            for (int nj = 0; nj < 4; nj++)
                acc[mi][nj] = __builtin_amdgcn_mfma_f32_16x16x32_bf16(
                    bfr[nj], af[mi], acc[mi][nj], 0, 0, 0);
        __syncthreads();   // protect LDS before next iter's staging
    }

    // swapped-operand C layout: per lane, token row = lrow, 4 consecutive n
#pragma unroll
    for (int mi = 0; mi < 4; mi++) {
        size_t rb = (size_t)(row0 + wm + mi * 16 + lrow) * INTER + n0 + wn + q * 4;
#pragma unroll
        for (int nj = 0; nj < 4; nj++) {
            f32x4 v = acc[mi][nj];
            bf16x4 o = { (bf16_t)(v.x / (1.f + __expf(-v.x))),
                         (bf16_t)(v.y / (1.f + __expf(-v.y))),
                         (bf16_t)(v.z / (1.f + __expf(-v.z))),
                         (bf16_t)(v.w / (1.f + __expf(-v.w))) };
            *(bf16x4*)(Hbuf + rb + nj * 16) = o;
        }
    }
}

// ---------------- GEMM2: Obuf = Hbuf[rows] @ W2[e] (unweighted partials) ------
__global__ __launch_bounds__(256) void gemm2_kernel(
    const bf16_t* __restrict__ Hbuf, const bf16_t* __restrict__ w2t,
    const int* __restrict__ hdr, bf16_t* __restrict__ Obuf)
{
    __shared__ __align__(16) bf16_t As[BM * BK];
    __shared__ __align__(16) bf16_t Bs[BN * BK];

    int row0 = blockIdx.x * BM;
    int e = tile_expert(hdr, row0);
    if (e < 0) return;
    int n0 = blockIdx.y * BN;
    int tid = threadIdx.x;

    int ar0 = tid >> 2, as0 = tid & 3, ak0 = as0 ^ (ar0 & 3);
    int ar1 = ar0 + 64, ak1 = as0 ^ (ar1 & 3);
    const bf16_t* ag0 = Hbuf + (size_t)(row0 + ar0) * INTER + ak0 * 8;
    const bf16_t* ag1 = Hbuf + (size_t)(row0 + ar1) * INTER + ak1 * 8;
    bf16_t* al0 = As + tid * 8;
    bf16_t* al1 = As + (tid + 256) * 8;

    const bf16_t* wb = w2t + (size_t)e * HIDDEN * INTER;  // [n=h][k=i]
    const bf16_t* bg0 = wb + (size_t)(n0 + ar0) * INTER + ak0 * 8;
    const bf16_t* bg1 = wb + (size_t)(n0 + ar1) * INTER + ak1 * 8;
    bf16_t* bl0 = Bs + tid * 8;
    bf16_t* bl1 = Bs + (tid + 256) * 8;

    int wave = tid >> 6, lane = tid & 63;
    int wm = (wave >> 1) * 64, wn = (wave & 1) * 64;
    int lrow = lane & 15, q = lane >> 4;

    int aoff[4], boff[4];
#pragma unroll
    for (int i = 0; i < 4; i++) {
        int r = wm + i * 16 + lrow;
        aoff[i] = r * BK + (q ^ (r & 3)) * 8;
        int s = wn + i * 16 + lrow;
        boff[i] = s * BK + (q ^ (s & 3)) * 8;
    }

    f32x4 acc[4][4] = {};

    for (int k0 = 0; k0 < INTER; k0 += BK) {
        async_cp16(ag0 + k0, al0);
        async_cp16(ag1 + k0, al1);
        async_cp16(bg0 + k0, bl0);
        async_cp16(bg1 + k0, bl1);
        __syncthreads();
        bf16x8 af[4], bfr[4];
#pragma unroll
        for (int i = 0; i < 4; i++) {
            af[i]  = *(const bf16x8*)(As + aoff[i]);
            bfr[i] = *(const bf16x8*)(Bs + boff[i]);
        }
#pragma unroll
        for (int mi = 0; mi < 4; mi++)
#pragma unroll
            for (int nj = 0; nj < 4; nj++)
                acc[mi][nj] = __builtin_amdgcn_mfma_f32_16x16x32_bf16(
                    bfr[nj], af[mi], acc[mi][nj], 0, 0, 0);
        __syncthreads();
    }

#pragma unroll
    for (int mi = 0; mi < 4; mi++) {
        size_t rb = (size_t)(row0 + wm + mi * 16 + lrow) * HIDDEN + n0 + wn + q * 4;
#pragma unroll
        for (int nj = 0; nj < 4; nj++) {
            f32x4 v = acc[mi][nj];
            bf16x4 o = { (bf16_t)v.x, (bf16_t)v.y, (bf16_t)v.z, (bf16_t)v.w };
            *(bf16x4*)(Obuf + rb + nj * 16) = o;
        }
    }
}

// ---------------- Combine: out[t] = w0*Obuf[r0] + w1*Obuf[r1] -----------------
__global__ __launch_bounds__(256) void combine_kernel(
    const bf16_t* __restrict__ Obuf, const int* __restrict__ row_of,
    const float* __restrict__ top_w, float* __restrict__ out)
{
    int t = blockIdx.x;
    int r0 = row_of[t * 2 + 0], r1 = row_of[t * 2 + 1];
    float w0 = top_w[t * 2 + 0], w1 = top_w[t * 2 + 1];
    int c = threadIdx.x * 4;
    bf16x4 a = *(const bf16x4*)(Obuf + (size_t)r0 * HIDDEN + c);
    bf16x4 b = *(const bf16x4*)(Obuf + (size_t)r1 * HIDDEN + c);
    float4 o;
    o.x = w0 * (float)a.x + w1 * (float)b.x;
    o.y = w0 * (float)a.y + w1 * (float)b.y;
    o.z = w0 * (float)a.z + w1 * (float)b.z;
    o.w = w0 * (float)a.w + w1 * (float)b.w;
    *(float4*)(out + (size_t)t * HIDDEN + c) = o;
}

// ---------------- Launch ------------------------------------------------------
extern "C" void kernel_launch(void* const* d_in, const int* in_sizes, int n_in,
                              void* d_out, int out_size, void* d_ws, size_t ws_size,
                              hipStream_t stream)
{
    const float* x  = (const float*)d_in[0];
    const float* wr = (const float*)d_in[1];
    const float* w1 = (const float*)d_in[2];
    const float* w2 = (const float*)d_in[3];
    float* out = (float*)d_out;

    int n = in_sizes[0] / HIDDEN;                       // 8192
    int rowcap = ((2 * n + NEXP * (BM - 1)) + BM - 1) / BM * BM;   // 17408

    char* ws = (char*)d_ws;
    int*   hdr       = (int*)ws;                        // 256 B
    float* probs_sum = (float*)(ws + 256);              // 32 B
    size_t off = 512;
    int* row_tok = (int*)(ws + off); off += (size_t)rowcap * 4;
    int* row_of  = (int*)(ws + off); off += (size_t)n * 2 * 4;
    int* top_e   = (int*)(ws + off); off += (size_t)n * 2 * 4;
    float* top_w = (float*)(ws + off); off += (size_t)n * 2 * 4;
    off = (off + 255) & ~(size_t)255;
    size_t xbf_off = off;
    bf16_t* xbf = (bf16_t*)(ws + off);  off += (size_t)n * HIDDEN * 2;
    bf16_t* w1t = (bf16_t*)(ws + off);  off += (size_t)NEXP * HIDDEN * INTER * 2;
    bf16_t* w2t = (bf16_t*)(ws + off);  off += (size_t)NEXP * HIDDEN * INTER * 2;
    bf16_t* Hbuf = (bf16_t*)(ws + off); off += (size_t)rowcap * INTER * 2;
    // Obuf aliases [xbf, w1t] — both dead after gemm1; Obuf fits (35.7<50.3 MB)
    bf16_t* Obuf = (bf16_t*)(ws + xbf_off);

    hipMemsetAsync(ws, 0, 512, stream);
    hipMemsetAsync(row_tok, 0xFF, (size_t)rowcap * 4, stream);

    router_kernel<<<n / 4, 256, 0, stream>>>(x, wr, top_e, top_w, hdr, probs_sum);
    cvt_x_kernel<<<(n * HIDDEN) / 1024, 256, 0, stream>>>(x, xbf);
    transpose_cvt_kernel<<<dim3(INTER / 32, HIDDEN / 32, NEXP), 256, 0, stream>>>(
        w1, w1t, HIDDEN, INTER);
    transpose_cvt_kernel<<<dim3(HIDDEN / 32, INTER / 32, NEXP), 256, 0, stream>>>(
        w2, w2t, INTER, HIDDEN);
    setup_kernel<<<1, 64, 0, stream>>>(hdr, probs_sum, out + (out_size - 1), n);
    scatter_kernel<<<(n + 255) / 256, 256, 0, stream>>>(top_e, hdr, row_tok, row_of, n);

    dim3 g1(rowcap / BM, INTER / BN);
    gemm1_kernel<<<g1, 256, 0, stream>>>(xbf, w1t, hdr, row_tok, Hbuf);
    dim3 g2(rowcap / BM, HIDDEN / BN);
    gemm2_kernel<<<g2, 256, 0, stream>>>(Hbuf, w2t, hdr, Obuf);
    combine_kernel<<<n, 256, 0, stream>>>(Obuf, row_of, top_w, out);
}

// Round 3
// 826.413 us; speedup vs baseline: 3.6272x; 1.0161x over previous
//
#include <hip/hip_runtime.h>
#include <hip/hip_bf16.h>

#define HIDDEN 1024
#define INTER  2048
#define NEXP   8
#define BM 128
#define BN 128
#define BK 32

typedef __bf16 bf16_t;
typedef __bf16 bf16x4 __attribute__((ext_vector_type(4)));
typedef __bf16 bf16x8 __attribute__((ext_vector_type(8)));
typedef float  f32x4  __attribute__((ext_vector_type(4)));

// async 16B global->LDS (DMA, no VGPR round-trip). LDS dest must be
// wave-uniform base + lane*16 — our chunk mapping guarantees it.
__device__ __forceinline__ void async_cp16(const bf16_t* g, bf16_t* l) {
    __builtin_amdgcn_global_load_lds(
        (const __attribute__((address_space(1))) unsigned int*)g,
        (__attribute__((address_space(3))) unsigned int*)l, 16, 0, 0);
}

// hdr: [0..7]=cnt2 [8..15]=cnt1 [16..23]=cursor [24..31]=seg_base [32..39]=seg_cap

// ---------------- Router: fp64 logits, LDS-staged wr, fused x->bf16 -----------
// Selection ordering done on fp64 logits (== softmax prob ordering).
__global__ __launch_bounds__(256) void router_kernel(
    const float* __restrict__ x, const float* __restrict__ wr,
    int* __restrict__ top_e, float* __restrict__ top_w,
    int* __restrict__ hdr, float* __restrict__ probs_sum,
    bf16_t* __restrict__ xbf)
{
    __shared__ float wl[NEXP * HIDDEN];   // [e][h], 32 KB
    __shared__ float psum[NEXP];
    int tid = threadIdx.x;
    if (tid < NEXP) psum[tid] = 0.f;

    // stage wr [h][e] -> LDS [e][h]; per float4: same h, e = m%8..m%8+3
    for (int i = tid; i < HIDDEN * NEXP / 4; i += 256) {
        float4 v = *(const float4*)(wr + i * 4);
        int m = i * 4, h = m >> 3, e = m & 7;
        wl[(e + 0) * HIDDEN + h] = v.x;
        wl[(e + 1) * HIDDEN + h] = v.y;
        wl[(e + 2) * HIDDEN + h] = v.z;
        wl[(e + 3) * HIDDEN + h] = v.w;
    }
    __syncthreads();

    int lane = tid & 63;
    int tok = blockIdx.x * 4 + (tid >> 6);
    const float* xr = x + (size_t)tok * HIDDEN;

    // 16 independent coalesced loads (fully unrolled, all in flight)
    float xv[16];
#pragma unroll
    for (int j = 0; j < 16; j++) xv[j] = xr[lane + 64 * j];

    // fused x -> bf16 (contiguous 128B per store across the wave)
    bf16_t* xbr = xbf + (size_t)tok * HIDDEN;
#pragma unroll
    for (int j = 0; j < 16; j++) xbr[lane + 64 * j] = (bf16_t)xv[j];

    double acc[NEXP];
#pragma unroll
    for (int e = 0; e < NEXP; e++) acc[e] = 0.0;
#pragma unroll
    for (int j = 0; j < 16; j++) {
        int h = lane + 64 * j;
#pragma unroll
        for (int e = 0; e < NEXP; e++)
            acc[e] += (double)xv[j] * (double)wl[e * HIDDEN + h];  // 2-way LDS: free
    }
#pragma unroll
    for (int e = 0; e < NEXP; e++) {
        double v = acc[e];
#pragma unroll
        for (int off = 32; off > 0; off >>= 1) v += __shfl_down(v, off);
        acc[e] = v;
    }
    if (lane == 0) {
        // top-2 on logits; strict > keeps lowest index on ties (lax.top_k)
        int e0 = 0;
#pragma unroll
        for (int e = 1; e < NEXP; e++) if (acc[e] > acc[e0]) e0 = e;
        int e1 = (e0 == 0) ? 1 : 0;
#pragma unroll
        for (int e = 0; e < NEXP; e++) if (e != e0 && acc[e] > acc[e1]) e1 = e;
        double w0 = 1.0 / (1.0 + exp(acc[e1] - acc[e0]));   // p0/(p0+p1), one fp64 exp
        top_e[tok * 2 + 0] = e0;
        top_e[tok * 2 + 1] = e1;
        top_w[tok * 2 + 0] = (float)w0;
        top_w[tok * 2 + 1] = (float)(1.0 - w0);
        atomicAdd(&hdr[8 + e0], 1);
        atomicAdd(&hdr[0 + e0], 1);
        atomicAdd(&hdr[0 + e1], 1);
        // fp32 softmax probs for aux loss (error-tolerant)
        float mx = (float)acc[0];
#pragma unroll
        for (int e = 1; e < NEXP; e++) mx = fmaxf(mx, (float)acc[e]);
        float p[NEXP], s = 0.f;
#pragma unroll
        for (int e = 0; e < NEXP; e++) { p[e] = __expf((float)acc[e] - mx); s += p[e]; }
#pragma unroll
        for (int e = 0; e < NEXP; e++) atomicAdd(&psum[e], p[e] / s);
    }
    __syncthreads();
    if (tid < NEXP) atomicAdd(&probs_sum[tid], psum[tid]);
}

// ---------------- Segment setup + aux loss ------------------------------------
__global__ void setup_kernel(int* __restrict__ hdr,
                             const float* __restrict__ probs_sum,
                             float* __restrict__ aux_out, int n)
{
    if (threadIdx.x == 0 && blockIdx.x == 0) {
        int off = 0;
        for (int e = 0; e < NEXP; e++) {
            hdr[24 + e] = off;
            int cap = (hdr[e] + BM - 1) / BM * BM;
            hdr[32 + e] = cap;
            off += cap;
        }
        double aux = 0.0;
        for (int e = 0; e < NEXP; e++)
            aux += ((double)hdr[8 + e] / n) * ((double)probs_sum[e] / n);
        *aux_out = (float)(aux * NEXP);
    }
}

// ---------------- Scatter: token -> expert-segment rows -----------------------
__global__ __launch_bounds__(256) void scatter_kernel(
    const int* __restrict__ top_e, int* __restrict__ hdr,
    int* __restrict__ row_tok, int* __restrict__ row_of, int n)
{
    int t = blockIdx.x * 256 + threadIdx.x;
    if (t >= n) return;
#pragma unroll
    for (int k = 0; k < 2; k++) {
        int e = top_e[t * 2 + k];
        int pos = atomicAdd(&hdr[16 + e], 1);
        int row = hdr[24 + e] + pos;
        row_tok[row] = t;
        row_of[t * 2 + k] = row;
    }
}

// ---------------- per-expert transpose-convert [R][C]f32 -> [C][R]bf16 --------
__global__ __launch_bounds__(256) void transpose_cvt_kernel(
    const float* __restrict__ src, bf16_t* __restrict__ dst, int R, int C)
{
    __shared__ float tile[32][33];
    int e = blockIdx.z;
    int r0 = blockIdx.y * 32, c0 = blockIdx.x * 32;
    int tid = threadIdx.x;
    int r = tid >> 3, cq = (tid & 7) * 4;
    const float* s = src + ((size_t)e * R + r0 + r) * C + c0 + cq;
    float4 v = *(const float4*)s;
    tile[r][cq + 0] = v.x; tile[r][cq + 1] = v.y;
    tile[r][cq + 2] = v.z; tile[r][cq + 3] = v.w;
    __syncthreads();
    int c = tid >> 3, rq = (tid & 7) * 4;
    bf16x4 o = { (bf16_t)tile[rq + 0][c], (bf16_t)tile[rq + 1][c],
                 (bf16_t)tile[rq + 2][c], (bf16_t)tile[rq + 3][c] };
    *(bf16x4*)(dst + ((size_t)e * C + c0 + c) * R + r0 + rq) = o;
}

// ---------------- expert lookup ----------------------------------------------
__device__ __forceinline__ int tile_expert(const int* hdr, int row0)
{
    int e = -1;
#pragma unroll
    for (int i = 0; i < NEXP; i++) {
        int sb = hdr[24 + i];
        if (row0 >= sb && row0 < sb + hdr[32 + i]) e = i;
    }
    if (e >= 0 && row0 - hdr[24 + e] >= hdr[e]) e = -1;  // tile fully padding
    return e;
}

// ---------------- GEMM1: Hbuf = silu(X[rows] @ W1[e]) bf16 MFMA ---------------
__global__ __launch_bounds__(256) void gemm1_kernel(
    const bf16_t* __restrict__ xbf, const bf16_t* __restrict__ w1t,
    const int* __restrict__ hdr, const int* __restrict__ row_tok,
    bf16_t* __restrict__ Hbuf)
{
    __shared__ __align__(16) bf16_t As[BM * BK];
    __shared__ __align__(16) bf16_t Bs[BN * BK];

    int row0 = blockIdx.x * BM;
    int e = tile_expert(hdr, row0);
    if (e < 0) return;
    int n0 = blockIdx.y * BN;
    int tid = threadIdx.x;

    int ar0 = tid >> 2, as0 = tid & 3, ak0 = as0 ^ (ar0 & 3);
    int ar1 = ar0 + 64, ak1 = as0 ^ (ar1 & 3);
    int t0 = row_tok[row0 + ar0]; if (t0 < 0) t0 = 0;
    int t1 = row_tok[row0 + ar1]; if (t1 < 0) t1 = 0;
    const bf16_t* ag0 = xbf + (size_t)t0 * HIDDEN + ak0 * 8;
    const bf16_t* ag1 = xbf + (size_t)t1 * HIDDEN + ak1 * 8;
    bf16_t* al0 = As + tid * 8;
    bf16_t* al1 = As + (tid + 256) * 8;

    const bf16_t* wb = w1t + (size_t)e * HIDDEN * INTER;  // [n][k]
    const bf16_t* bg0 = wb + (size_t)(n0 + ar0) * HIDDEN + ak0 * 8;
    const bf16_t* bg1 = wb + (size_t)(n0 + ar1) * HIDDEN + ak1 * 8;
    bf16_t* bl0 = Bs + tid * 8;
    bf16_t* bl1 = Bs + (tid + 256) * 8;

    int wave = tid >> 6, lane = tid & 63;
    int wm = (wave >> 1) * 64, wn = (wave & 1) * 64;
    int lrow = lane & 15, q = lane >> 4;

    int aoff[4], boff[4];
#pragma unroll
    for (int i = 0; i < 4; i++) {
        int r = wm + i * 16 + lrow;
        aoff[i] = r * BK + (q ^ (r & 3)) * 8;
        int s = wn + i * 16 + lrow;
        boff[i] = s * BK + (q ^ (s & 3)) * 8;
    }

    f32x4 acc[4][4] = {};

    for (int k0 = 0; k0 < HIDDEN; k0 += BK) {
        async_cp16(ag0 + k0, al0);
        async_cp16(ag1 + k0, al1);
        async_cp16(bg0 + k0, bl0);
        async_cp16(bg1 + k0, bl1);
        __syncthreads();
        bf16x8 af[4], bfr[4];
#pragma unroll
        for (int i = 0; i < 4; i++) {
            af[i]  = *(const bf16x8*)(As + aoff[i]);
            bfr[i] = *(const bf16x8*)(Bs + boff[i]);
        }
#pragma unroll
        for (int mi = 0; mi < 4; mi++)
#pragma unroll
            for (int nj = 0; nj < 4; nj++)
                acc[mi][nj] = __builtin_amdgcn_mfma_f32_16x16x32_bf16(
                    bfr[nj], af[mi], acc[mi][nj], 0, 0, 0);
        __syncthreads();
    }

#pragma unroll
    for (int mi = 0; mi < 4; mi++) {
        size_t rb = (size_t)(row0 + wm + mi * 16 + lrow) * INTER + n0 + wn + q * 4;
#pragma unroll
        for (int nj = 0; nj < 4; nj++) {
            f32x4 v = acc[mi][nj];
            bf16x4 o = { (bf16_t)(v.x / (1.f + __expf(-v.x))),
                         (bf16_t)(v.y / (1.f + __expf(-v.y))),
                         (bf16_t)(v.z / (1.f + __expf(-v.z))),
                         (bf16_t)(v.w / (1.f + __expf(-v.w))) };
            *(bf16x4*)(Hbuf + rb + nj * 16) = o;
        }
    }
}

// ---------------- GEMM2: Obuf = Hbuf[rows] @ W2[e] (unweighted partials) ------
__global__ __launch_bounds__(256) void gemm2_kernel(
    const bf16_t* __restrict__ Hbuf, const bf16_t* __restrict__ w2t,
    const int* __restrict__ hdr, bf16_t* __restrict__ Obuf)
{
    __shared__ __align__(16) bf16_t As[BM * BK];
    __shared__ __align__(16) bf16_t Bs[BN * BK];

    int row0 = blockIdx.x * BM;
    int e = tile_expert(hdr, row0);
    if (e < 0) return;
    int n0 = blockIdx.y * BN;
    int tid = threadIdx.x;

    int ar0 = tid >> 2, as0 = tid & 3, ak0 = as0 ^ (ar0 & 3);
    int ar1 = ar0 + 64, ak1 = as0 ^ (ar1 & 3);
    const bf16_t* ag0 = Hbuf + (size_t)(row0 + ar0) * INTER + ak0 * 8;
    const bf16_t* ag1 = Hbuf + (size_t)(row0 + ar1) * INTER + ak1 * 8;
    bf16_t* al0 = As + tid * 8;
    bf16_t* al1 = As + (tid + 256) * 8;

    const bf16_t* wb = w2t + (size_t)e * HIDDEN * INTER;  // [n=h][k=i]
    const bf16_t* bg0 = wb + (size_t)(n0 + ar0) * INTER + ak0 * 8;
    const bf16_t* bg1 = wb + (size_t)(n0 + ar1) * INTER + ak1 * 8;
    bf16_t* bl0 = Bs + tid * 8;
    bf16_t* bl1 = Bs + (tid + 256) * 8;

    int wave = tid >> 6, lane = tid & 63;
    int wm = (wave >> 1) * 64, wn = (wave & 1) * 64;
    int lrow = lane & 15, q = lane >> 4;

    int aoff[4], boff[4];
#pragma unroll
    for (int i = 0; i < 4; i++) {
        int r = wm + i * 16 + lrow;
        aoff[i] = r * BK + (q ^ (r & 3)) * 8;
        int s = wn + i * 16 + lrow;
        boff[i] = s * BK + (q ^ (s & 3)) * 8;
    }

    f32x4 acc[4][4] = {};

    for (int k0 = 0; k0 < INTER; k0 += BK) {
        async_cp16(ag0 + k0, al0);
        async_cp16(ag1 + k0, al1);
        async_cp16(bg0 + k0, bl0);
        async_cp16(bg1 + k0, bl1);
        __syncthreads();
        bf16x8 af[4], bfr[4];
#pragma unroll
        for (int i = 0; i < 4; i++) {
            af[i]  = *(const bf16x8*)(As + aoff[i]);
            bfr[i] = *(const bf16x8*)(Bs + boff[i]);
        }
#pragma unroll
        for (int mi = 0; mi < 4; mi++)
#pragma unroll
            for (int nj = 0; nj < 4; nj++)
                acc[mi][nj] = __builtin_amdgcn_mfma_f32_16x16x32_bf16(
                    bfr[nj], af[mi], acc[mi][nj], 0, 0, 0);
        __syncthreads();
    }

#pragma unroll
    for (int mi = 0; mi < 4; mi++) {
        size_t rb = (size_t)(row0 + wm + mi * 16 + lrow) * HIDDEN + n0 + wn + q * 4;
#pragma unroll
        for (int nj = 0; nj < 4; nj++) {
            f32x4 v = acc[mi][nj];
            bf16x4 o = { (bf16_t)v.x, (bf16_t)v.y, (bf16_t)v.z, (bf16_t)v.w };
            *(bf16x4*)(Obuf + rb + nj * 16) = o;
        }
    }
}

// ---------------- Combine: out[t] = w0*Obuf[r0] + w1*Obuf[r1] -----------------
__global__ __launch_bounds__(256) void combine_kernel(
    const bf16_t* __restrict__ Obuf, const int* __restrict__ row_of,
    const float* __restrict__ top_w, float* __restrict__ out)
{
    int t = blockIdx.x;
    int r0 = row_of[t * 2 + 0], r1 = row_of[t * 2 + 1];
    float w0 = top_w[t * 2 + 0], w1 = top_w[t * 2 + 1];
    int c = threadIdx.x * 4;
    bf16x4 a = *(const bf16x4*)(Obuf + (size_t)r0 * HIDDEN + c);
    bf16x4 b = *(const bf16x4*)(Obuf + (size_t)r1 * HIDDEN + c);
    float4 o;
    o.x = w0 * (float)a.x + w1 * (float)b.x;
    o.y = w0 * (float)a.y + w1 * (float)b.y;
    o.z = w0 * (float)a.z + w1 * (float)b.z;
    o.w = w0 * (float)a.w + w1 * (float)b.w;
    *(float4*)(out + (size_t)t * HIDDEN + c) = o;
}

// ---------------- Launch ------------------------------------------------------
extern "C" void kernel_launch(void* const* d_in, const int* in_sizes, int n_in,
                              void* d_out, int out_size, void* d_ws, size_t ws_size,
                              hipStream_t stream)
{
    const float* x  = (const float*)d_in[0];
    const float* wr = (const float*)d_in[1];
    const float* w1 = (const float*)d_in[2];
    const float* w2 = (const float*)d_in[3];
    float* out = (float*)d_out;

    int n = in_sizes[0] / HIDDEN;                       // 8192
    int rowcap = ((2 * n + NEXP * (BM - 1)) + BM - 1) / BM * BM;   // 17408

    char* ws = (char*)d_ws;
    int*   hdr       = (int*)ws;                        // 256 B
    float* probs_sum = (float*)(ws + 256);              // 32 B
    size_t off = 512;
    int* row_tok = (int*)(ws + off); off += (size_t)rowcap * 4;
    int* row_of  = (int*)(ws + off); off += (size_t)n * 2 * 4;
    int* top_e   = (int*)(ws + off); off += (size_t)n * 2 * 4;
    float* top_w = (float*)(ws + off); off += (size_t)n * 2 * 4;
    off = (off + 255) & ~(size_t)255;
    size_t xbf_off = off;
    bf16_t* xbf = (bf16_t*)(ws + off);  off += (size_t)n * HIDDEN * 2;
    bf16_t* w1t = (bf16_t*)(ws + off);  off += (size_t)NEXP * HIDDEN * INTER * 2;
    bf16_t* w2t = (bf16_t*)(ws + off);  off += (size_t)NEXP * HIDDEN * INTER * 2;
    bf16_t* Hbuf = (bf16_t*)(ws + off); off += (size_t)rowcap * INTER * 2;
    // Obuf aliases [xbf, w1t] — both dead after gemm1; Obuf fits (35.7<50.3 MB)
    bf16_t* Obuf = (bf16_t*)(ws + xbf_off);

    hipMemsetAsync(ws, 0, 512, stream);
    hipMemsetAsync(row_tok, 0xFF, (size_t)rowcap * 4, stream);

    router_kernel<<<n / 4, 256, 0, stream>>>(x, wr, top_e, top_w, hdr, probs_sum, xbf);
    transpose_cvt_kernel<<<dim3(INTER / 32, HIDDEN / 32, NEXP), 256, 0, stream>>>(
        w1, w1t, HIDDEN, INTER);
    transpose_cvt_kernel<<<dim3(HIDDEN / 32, INTER / 32, NEXP), 256, 0, stream>>>(
        w2, w2t, INTER, HIDDEN);
    setup_kernel<<<1, 64, 0, stream>>>(hdr, probs_sum, out + (out_size - 1), n);
    scatter_kernel<<<(n + 255) / 256, 256, 0, stream>>>(top_e, hdr, row_tok, row_of, n);

    dim3 g1(rowcap / BM, INTER / BN);
    gemm1_kernel<<<g1, 256, 0, stream>>>(xbf, w1t, hdr, row_tok, Hbuf);
    dim3 g2(rowcap / BM, HIDDEN / BN);
    gemm2_kernel<<<g2, 256, 0, stream>>>(Hbuf, w2t, hdr, Obuf);
    combine_kernel<<<n, 256, 0, stream>>>(Obuf, row_of, top_w, out);
}

// Round 4
// 525.294 us; speedup vs baseline: 5.7064x; 1.5732x over previous
//
#include <hip/hip_runtime.h>
#include <hip/hip_bf16.h>

#define HIDDEN 1024
#define INTER  2048
#define NEXP   8
#define BM 128
#define BN 128
#define BK 32

typedef __bf16 bf16_t;
typedef __bf16 bf16x4 __attribute__((ext_vector_type(4)));
typedef __bf16 bf16x8 __attribute__((ext_vector_type(8)));
typedef float  f32x4  __attribute__((ext_vector_type(4)));

__device__ __forceinline__ void async_cp16(const bf16_t* g, bf16_t* l) {
    __builtin_amdgcn_global_load_lds(
        (const __attribute__((address_space(1))) unsigned int*)g,
        (__attribute__((address_space(3))) unsigned int*)l, 16, 0, 0);
}

// hdr: [0..7]=cnt2 [8..15]=cnt1 [24..31]=seg_base [32..39]=seg_cap

// ---------------- Router: fp64 logits, NO global atomics ----------------------
__global__ __launch_bounds__(256) void router_kernel(
    const float* __restrict__ x, const float* __restrict__ wr,
    int* __restrict__ top_e, float* __restrict__ top_w,
    float* __restrict__ psums, bf16_t* __restrict__ xbf)
{
    __shared__ float wl[NEXP * HIDDEN];   // [e][h], 32 KB
    __shared__ float psl[4][NEXP];
    int tid = threadIdx.x;

    for (int i = tid; i < HIDDEN * NEXP / 4; i += 256) {
        float4 v = *(const float4*)(wr + i * 4);
        int m = i * 4, h = m >> 3, e = m & 7;
        wl[(e + 0) * HIDDEN + h] = v.x;
        wl[(e + 1) * HIDDEN + h] = v.y;
        wl[(e + 2) * HIDDEN + h] = v.z;
        wl[(e + 3) * HIDDEN + h] = v.w;
    }
    __syncthreads();

    int lane = tid & 63, wave = tid >> 6;
    int tok = blockIdx.x * 4 + wave;
    const float* xr = x + (size_t)tok * HIDDEN;

    float xv[16];
#pragma unroll
    for (int j = 0; j < 16; j++) xv[j] = xr[lane + 64 * j];

    bf16_t* xbr = xbf + (size_t)tok * HIDDEN;
#pragma unroll
    for (int j = 0; j < 16; j++) xbr[lane + 64 * j] = (bf16_t)xv[j];

    double acc[NEXP];
#pragma unroll
    for (int e = 0; e < NEXP; e++) acc[e] = 0.0;
#pragma unroll
    for (int j = 0; j < 16; j++) {
        int h = lane + 64 * j;
#pragma unroll
        for (int e = 0; e < NEXP; e++)
            acc[e] += (double)xv[j] * (double)wl[e * HIDDEN + h];
    }
#pragma unroll
    for (int e = 0; e < NEXP; e++) {
        double v = acc[e];
#pragma unroll
        for (int off = 32; off > 0; off >>= 1) v += __shfl_down(v, off);
        acc[e] = v;
    }
    if (lane == 0) {
        int e0 = 0;
#pragma unroll
        for (int e = 1; e < NEXP; e++) if (acc[e] > acc[e0]) e0 = e;
        int e1 = (e0 == 0) ? 1 : 0;
#pragma unroll
        for (int e = 0; e < NEXP; e++) if (e != e0 && acc[e] > acc[e1]) e1 = e;
        double w0 = 1.0 / (1.0 + exp(acc[e1] - acc[e0]));
        top_e[tok * 2 + 0] = e0;
        top_e[tok * 2 + 1] = e1;
        top_w[tok * 2 + 0] = (float)w0;
        top_w[tok * 2 + 1] = (float)(1.0 - w0);
        // fp32 softmax probs for aux loss (error-tolerant)
        float mx = (float)acc[0];
#pragma unroll
        for (int e = 1; e < NEXP; e++) mx = fmaxf(mx, (float)acc[e]);
        float p[NEXP], s = 0.f;
#pragma unroll
        for (int e = 0; e < NEXP; e++) { p[e] = __expf((float)acc[e] - mx); s += p[e]; }
#pragma unroll
        for (int e = 0; e < NEXP; e++) psl[wave][e] = p[e] / s;
    }
    __syncthreads();
    if (tid < NEXP)
        psums[blockIdx.x * NEXP + tid] =
            psl[0][tid] + psl[1][tid] + psl[2][tid] + psl[3][tid];
}

// ------- Single-block: histogram + segments + aux + deterministic scatter -----
__global__ __launch_bounds__(256) void setup_scatter_kernel(
    const int* __restrict__ top_e, const float* __restrict__ psums, int nblk,
    int* __restrict__ hdr, int* __restrict__ row_tok, int* __restrict__ row_of,
    float* __restrict__ aux_out, int n)
{
    __shared__ int wcnt[4][16];
    __shared__ int sc1[NEXP], sc2[NEXP], segb[NEXP], segc[NEXP], cur[NEXP];
    __shared__ int woff[4][16];      // [wave][e]=k0 count, [wave][8+e]=k1 count
    __shared__ float pred[NEXP];

    int tid = threadIdx.x, lane = tid & 63, wave = tid >> 6;
    if (tid < NEXP) pred[tid] = 0.f;

    // ---- Phase A: histogram via ballots (no atomics)
    int c1[NEXP] = {}, c2[NEXP] = {};
    for (int base = 0; base < n; base += 256) {
        int t = base + tid;
        int e0 = top_e[t * 2 + 0];
        int e1 = top_e[t * 2 + 1];
#pragma unroll
        for (int e = 0; e < NEXP; e++) {
            unsigned long long m0 = __ballot(e0 == e);
            unsigned long long m1 = __ballot(e1 == e);
            if (lane == 0) {
                c1[e] += __popcll(m0);
                c2[e] += __popcll(m0) + __popcll(m1);
            }
        }
    }
    if (lane == 0) {
#pragma unroll
        for (int e = 0; e < NEXP; e++) {
            wcnt[wave][e] = c2[e];
            wcnt[wave][8 + e] = c1[e];
        }
    }
    __syncthreads();
    if (tid < 16) {
        int s = wcnt[0][tid] + wcnt[1][tid] + wcnt[2][tid] + wcnt[3][tid];
        if (tid < 8) sc2[tid] = s; else sc1[tid - 8] = s;
    }
    __syncthreads();
    // ---- Phase B: segment bases + hdr
    if (tid == 0) {
        int off = 0;
#pragma unroll
        for (int e = 0; e < NEXP; e++) {
            segb[e] = off; cur[e] = off;
            int cap = (sc2[e] + BM - 1) / BM * BM;
            segc[e] = cap; off += cap;
            hdr[e] = sc2[e]; hdr[8 + e] = sc1[e];
            hdr[24 + e] = segb[e]; hdr[32 + e] = cap;
        }
    }
    // ---- Phase C: aux loss (psums reduce)
    {
        float ps = 0.f;
        int e = tid & 7;
        for (int i = tid >> 3; i < nblk; i += 32) ps += psums[i * NEXP + e];
        ps += __shfl_down(ps, 32);
        ps += __shfl_down(ps, 16);
        ps += __shfl_down(ps, 8);
        if (lane < 8) atomicAdd(&pred[lane], ps);   // LDS atomic, 4 waves x 8
    }
    __syncthreads();
    if (tid == 0) {
        double aux = 0.0;
#pragma unroll
        for (int e = 0; e < NEXP; e++)
            aux += ((double)sc1[e] / n) * ((double)pred[e] / n);
        *aux_out = (float)(aux * NEXP);
    }
    // ---- Phase E: padding rows -> -1
#pragma unroll
    for (int e = 0; e < NEXP; e++)
        for (int r = sc2[e] + tid; r < segc[e]; r += 256)
            row_tok[segb[e] + r] = -1;
    __syncthreads();

    // ---- Phase D: deterministic ballot-rank scatter (no atomics)
    for (int base = 0; base < n; base += 256) {
        int t = base + tid;
        int e0 = top_e[t * 2 + 0];
        int e1 = top_e[t * 2 + 1];
        unsigned long long below = (lane == 63) ? ~0ull >> 1 : (1ull << lane) - 1;
        int r0 = 0, r1 = 0;
#pragma unroll
        for (int e = 0; e < NEXP; e++) {
            unsigned long long m0 = __ballot(e0 == e);
            unsigned long long m1 = __ballot(e1 == e);
            if (e0 == e) r0 = __popcll(m0 & below);
            if (e1 == e) r1 = __popcll(m1 & below);
            if (lane == 0) {
                woff[wave][e] = __popcll(m0);
                woff[wave][8 + e] = __popcll(m1);
            }
        }
        __syncthreads();
        int pre0 = 0, tot0_e1 = 0, pre1 = 0;
#pragma unroll
        for (int w = 0; w < 4; w++) {
            if (w < wave) pre0 += woff[w][e0];
            tot0_e1 += woff[w][e1];
            if (w < wave) pre1 += woff[w][8 + e1];
        }
        int row0 = cur[e0] + pre0 + r0;
        int row1 = cur[e1] + tot0_e1 + pre1 + r1;
        row_tok[row0] = t;
        row_tok[row1] = t;
        row_of[t * 2 + 0] = row0;
        row_of[t * 2 + 1] = row1;
        __syncthreads();
        if (tid < 8)
            cur[tid] += woff[0][tid] + woff[1][tid] + woff[2][tid] + woff[3][tid]
                      + woff[0][8 + tid] + woff[1][8 + tid] + woff[2][8 + tid]
                      + woff[3][8 + tid];
        __syncthreads();
    }
}

// ---------------- per-expert transpose-convert [R][C]f32 -> [C][R]bf16 --------
__global__ __launch_bounds__(256) void transpose_cvt_kernel(
    const float* __restrict__ src, bf16_t* __restrict__ dst, int R, int C)
{
    __shared__ float tile[32][33];
    int e = blockIdx.z;
    int r0 = blockIdx.y * 32, c0 = blockIdx.x * 32;
    int tid = threadIdx.x;
    int r = tid >> 3, cq = (tid & 7) * 4;
    const float* s = src + ((size_t)e * R + r0 + r) * C + c0 + cq;
    float4 v = *(const float4*)s;
    tile[r][cq + 0] = v.x; tile[r][cq + 1] = v.y;
    tile[r][cq + 2] = v.z; tile[r][cq + 3] = v.w;
    __syncthreads();
    int c = tid >> 3, rq = (tid & 7) * 4;
    bf16x4 o = { (bf16_t)tile[rq + 0][c], (bf16_t)tile[rq + 1][c],
                 (bf16_t)tile[rq + 2][c], (bf16_t)tile[rq + 3][c] };
    *(bf16x4*)(dst + ((size_t)e * C + c0 + c) * R + r0 + rq) = o;
}

// ---------------- expert lookup ----------------------------------------------
__device__ __forceinline__ int tile_expert(const int* hdr, int row0)
{
    int e = -1;
#pragma unroll
    for (int i = 0; i < NEXP; i++) {
        int sb = hdr[24 + i];
        if (row0 >= sb && row0 < sb + hdr[32 + i]) e = i;
    }
    if (e >= 0 && row0 - hdr[24 + e] >= hdr[e]) e = -1;
    return e;
}

// ---------------- GEMM1: Hbuf = silu(X[rows] @ W1[e]) bf16 MFMA ---------------
__global__ __launch_bounds__(256) void gemm1_kernel(
    const bf16_t* __restrict__ xbf, const bf16_t* __restrict__ w1t,
    const int* __restrict__ hdr, const int* __restrict__ row_tok,
    bf16_t* __restrict__ Hbuf)
{
    __shared__ __align__(16) bf16_t As[BM * BK];
    __shared__ __align__(16) bf16_t Bs[BN * BK];

    int row0 = blockIdx.x * BM;
    int e = tile_expert(hdr, row0);
    if (e < 0) return;
    int n0 = blockIdx.y * BN;
    int tid = threadIdx.x;

    int ar0 = tid >> 2, as0 = tid & 3, ak0 = as0 ^ (ar0 & 3);
    int ar1 = ar0 + 64, ak1 = as0 ^ (ar1 & 3);
    int t0 = row_tok[row0 + ar0]; if (t0 < 0) t0 = 0;
    int t1 = row_tok[row0 + ar1]; if (t1 < 0) t1 = 0;
    const bf16_t* ag0 = xbf + (size_t)t0 * HIDDEN + ak0 * 8;
    const bf16_t* ag1 = xbf + (size_t)t1 * HIDDEN + ak1 * 8;
    bf16_t* al0 = As + tid * 8;
    bf16_t* al1 = As + (tid + 256) * 8;

    const bf16_t* wb = w1t + (size_t)e * HIDDEN * INTER;
    const bf16_t* bg0 = wb + (size_t)(n0 + ar0) * HIDDEN + ak0 * 8;
    const bf16_t* bg1 = wb + (size_t)(n0 + ar1) * HIDDEN + ak1 * 8;
    bf16_t* bl0 = Bs + tid * 8;
    bf16_t* bl1 = Bs + (tid + 256) * 8;

    int wave = tid >> 6, lane = tid & 63;
    int wm = (wave >> 1) * 64, wn = (wave & 1) * 64;
    int lrow = lane & 15, q = lane >> 4;

    int aoff[4], boff[4];
#pragma unroll
    for (int i = 0; i < 4; i++) {
        int r = wm + i * 16 + lrow;
        aoff[i] = r * BK + (q ^ (r & 3)) * 8;
        int s = wn + i * 16 + lrow;
        boff[i] = s * BK + (q ^ (s & 3)) * 8;
    }

    f32x4 acc[4][4] = {};

    for (int k0 = 0; k0 < HIDDEN; k0 += BK) {
        async_cp16(ag0 + k0, al0);
        async_cp16(ag1 + k0, al1);
        async_cp16(bg0 + k0, bl0);
        async_cp16(bg1 + k0, bl1);
        __syncthreads();
        bf16x8 af[4], bfr[4];
#pragma unroll
        for (int i = 0; i < 4; i++) {
            af[i]  = *(const bf16x8*)(As + aoff[i]);
            bfr[i] = *(const bf16x8*)(Bs + boff[i]);
        }
#pragma unroll
        for (int mi = 0; mi < 4; mi++)
#pragma unroll
            for (int nj = 0; nj < 4; nj++)
                acc[mi][nj] = __builtin_amdgcn_mfma_f32_16x16x32_bf16(
                    bfr[nj], af[mi], acc[mi][nj], 0, 0, 0);
        __syncthreads();
    }

#pragma unroll
    for (int mi = 0; mi < 4; mi++) {
        size_t rb = (size_t)(row0 + wm + mi * 16 + lrow) * INTER + n0 + wn + q * 4;
#pragma unroll
        for (int nj = 0; nj < 4; nj++) {
            f32x4 v = acc[mi][nj];
            bf16x4 o = { (bf16_t)(v.x / (1.f + __expf(-v.x))),
                         (bf16_t)(v.y / (1.f + __expf(-v.y))),
                         (bf16_t)(v.z / (1.f + __expf(-v.z))),
                         (bf16_t)(v.w / (1.f + __expf(-v.w))) };
            *(bf16x4*)(Hbuf + rb + nj * 16) = o;
        }
    }
}

// ---------------- GEMM2: Obuf = Hbuf[rows] @ W2[e] ----------------------------
__global__ __launch_bounds__(256) void gemm2_kernel(
    const bf16_t* __restrict__ Hbuf, const bf16_t* __restrict__ w2t,
    const int* __restrict__ hdr, bf16_t* __restrict__ Obuf)
{
    __shared__ __align__(16) bf16_t As[BM * BK];
    __shared__ __align__(16) bf16_t Bs[BN * BK];

    int row0 = blockIdx.x * BM;
    int e = tile_expert(hdr, row0);
    if (e < 0) return;
    int n0 = blockIdx.y * BN;
    int tid = threadIdx.x;

    int ar0 = tid >> 2, as0 = tid & 3, ak0 = as0 ^ (ar0 & 3);
    int ar1 = ar0 + 64, ak1 = as0 ^ (ar1 & 3);
    const bf16_t* ag0 = Hbuf + (size_t)(row0 + ar0) * INTER + ak0 * 8;
    const bf16_t* ag1 = Hbuf + (size_t)(row0 + ar1) * INTER + ak1 * 8;
    bf16_t* al0 = As + tid * 8;
    bf16_t* al1 = As + (tid + 256) * 8;

    const bf16_t* wb = w2t + (size_t)e * HIDDEN * INTER;
    const bf16_t* bg0 = wb + (size_t)(n0 + ar0) * INTER + ak0 * 8;
    const bf16_t* bg1 = wb + (size_t)(n0 + ar1) * INTER + ak1 * 8;
    bf16_t* bl0 = Bs + tid * 8;
    bf16_t* bl1 = Bs + (tid + 256) * 8;

    int wave = tid >> 6, lane = tid & 63;
    int wm = (wave >> 1) * 64, wn = (wave & 1) * 64;
    int lrow = lane & 15, q = lane >> 4;

    int aoff[4], boff[4];
#pragma unroll
    for (int i = 0; i < 4; i++) {
        int r = wm + i * 16 + lrow;
        aoff[i] = r * BK + (q ^ (r & 3)) * 8;
        int s = wn + i * 16 + lrow;
        boff[i] = s * BK + (q ^ (s & 3)) * 8;
    }

    f32x4 acc[4][4] = {};

    for (int k0 = 0; k0 < INTER; k0 += BK) {
        async_cp16(ag0 + k0, al0);
        async_cp16(ag1 + k0, al1);
        async_cp16(bg0 + k0, bl0);
        async_cp16(bg1 + k0, bl1);
        __syncthreads();
        bf16x8 af[4], bfr[4];
#pragma unroll
        for (int i = 0; i < 4; i++) {
            af[i]  = *(const bf16x8*)(As + aoff[i]);
            bfr[i] = *(const bf16x8*)(Bs + boff[i]);
        }
#pragma unroll
        for (int mi = 0; mi < 4; mi++)
#pragma unroll
            for (int nj = 0; nj < 4; nj++)
                acc[mi][nj] = __builtin_amdgcn_mfma_f32_16x16x32_bf16(
                    bfr[nj], af[mi], acc[mi][nj], 0, 0, 0);
        __syncthreads();
    }

#pragma unroll
    for (int mi = 0; mi < 4; mi++) {
        size_t rb = (size_t)(row0 + wm + mi * 16 + lrow) * HIDDEN + n0 + wn + q * 4;
#pragma unroll
        for (int nj = 0; nj < 4; nj++) {
            f32x4 v = acc[mi][nj];
            bf16x4 o = { (bf16_t)v.x, (bf16_t)v.y, (bf16_t)v.z, (bf16_t)v.w };
            *(bf16x4*)(Obuf + rb + nj * 16) = o;
        }
    }
}

// ---------------- Combine: out[t] = w0*Obuf[r0] + w1*Obuf[r1] -----------------
__global__ __launch_bounds__(256) void combine_kernel(
    const bf16_t* __restrict__ Obuf, const int* __restrict__ row_of,
    const float* __restrict__ top_w, float* __restrict__ out)
{
    int t = blockIdx.x;
    int r0 = row_of[t * 2 + 0], r1 = row_of[t * 2 + 1];
    float w0 = top_w[t * 2 + 0], w1 = top_w[t * 2 + 1];
    int c = threadIdx.x * 4;
    bf16x4 a = *(const bf16x4*)(Obuf + (size_t)r0 * HIDDEN + c);
    bf16x4 b = *(const bf16x4*)(Obuf + (size_t)r1 * HIDDEN + c);
    float4 o;
    o.x = w0 * (float)a.x + w1 * (float)b.x;
    o.y = w0 * (float)a.y + w1 * (float)b.y;
    o.z = w0 * (float)a.z + w1 * (float)b.z;
    o.w = w0 * (float)a.w + w1 * (float)b.w;
    *(float4*)(out + (size_t)t * HIDDEN + c) = o;
}

// ---------------- Launch ------------------------------------------------------
extern "C" void kernel_launch(void* const* d_in, const int* in_sizes, int n_in,
                              void* d_out, int out_size, void* d_ws, size_t ws_size,
                              hipStream_t stream)
{
    const float* x  = (const float*)d_in[0];
    const float* wr = (const float*)d_in[1];
    const float* w1 = (const float*)d_in[2];
    const float* w2 = (const float*)d_in[3];
    float* out = (float*)d_out;

    int n = in_sizes[0] / HIDDEN;                                  // 8192
    int nblk = n / 4;                                              // 2048
    int rowcap = ((2 * n + NEXP * (BM - 1)) + BM - 1) / BM * BM;   // 17408

    char* ws = (char*)d_ws;
    int* hdr = (int*)ws;                                // 256 B
    size_t off = 512;
    int* row_tok = (int*)(ws + off); off += (size_t)rowcap * 4;
    int* row_of  = (int*)(ws + off); off += (size_t)n * 2 * 4;
    int* top_e   = (int*)(ws + off); off += (size_t)n * 2 * 4;
    float* top_w = (float*)(ws + off); off += (size_t)n * 2 * 4;
    float* psums = (float*)(ws + off); off += (size_t)nblk * NEXP * 4;
    off = (off + 255) & ~(size_t)255;
    size_t xbf_off = off;
    bf16_t* xbf = (bf16_t*)(ws + off);  off += (size_t)n * HIDDEN * 2;
    bf16_t* w1t = (bf16_t*)(ws + off);  off += (size_t)NEXP * HIDDEN * INTER * 2;
    bf16_t* w2t = (bf16_t*)(ws + off);  off += (size_t)NEXP * HIDDEN * INTER * 2;
    bf16_t* Hbuf = (bf16_t*)(ws + off); off += (size_t)rowcap * INTER * 2;
    bf16_t* Obuf = (bf16_t*)(ws + xbf_off);   // aliases xbf+w1t (dead after gemm1)

    router_kernel<<<nblk, 256, 0, stream>>>(x, wr, top_e, top_w, psums, xbf);
    transpose_cvt_kernel<<<dim3(INTER / 32, HIDDEN / 32, NEXP), 256, 0, stream>>>(
        w1, w1t, HIDDEN, INTER);
    transpose_cvt_kernel<<<dim3(HIDDEN / 32, INTER / 32, NEXP), 256, 0, stream>>>(
        w2, w2t, INTER, HIDDEN);
    setup_scatter_kernel<<<1, 256, 0, stream>>>(top_e, psums, nblk, hdr,
                                                row_tok, row_of,
                                                out + (out_size - 1), n);

    dim3 g1(rowcap / BM, INTER / BN);
    gemm1_kernel<<<g1, 256, 0, stream>>>(xbf, w1t, hdr, row_tok, Hbuf);
    dim3 g2(rowcap / BM, HIDDEN / BN);
    gemm2_kernel<<<g2, 256, 0, stream>>>(Hbuf, w2t, hdr, Obuf);
    combine_kernel<<<n, 256, 0, stream>>>(Obuf, row_of, top_w, out);
}

// Round 5
// 492.859 us; speedup vs baseline: 6.0819x; 1.0658x over previous
//
#include <hip/hip_runtime.h>
#include <hip/hip_bf16.h>

#define HIDDEN 1024
#define INTER  2048
#define NEXP   8
#define BM 128
#define BN 128
#define BK 32

typedef __bf16 bf16_t;
typedef __bf16 bf16x4 __attribute__((ext_vector_type(4)));
typedef __bf16 bf16x8 __attribute__((ext_vector_type(8)));
typedef float  f32x4  __attribute__((ext_vector_type(4)));

__device__ __forceinline__ void async_cp16(const bf16_t* g, bf16_t* l) {
    __builtin_amdgcn_global_load_lds(
        (const __attribute__((address_space(1))) unsigned int*)g,
        (__attribute__((address_space(3))) unsigned int*)l, 16, 0, 0);
}

// bank-conflict-free chunk swizzle: any 8 consecutive rows hit 8 distinct
// bank bases; residual aliasing is the free 2-way (r, r+8).
__device__ __forceinline__ int swz(int r) { return (r >> 1) & 3; }

// hdr: [0..7]=cnt2 [8..15]=cnt1 [24..31]=seg_base [32..39]=seg_cap

// ---------------- Router: fp64 logits, NO global atomics ----------------------
__global__ __launch_bounds__(256) void router_kernel(
    const float* __restrict__ x, const float* __restrict__ wr,
    int* __restrict__ top_e, float* __restrict__ top_w,
    float* __restrict__ psums, bf16_t* __restrict__ xbf)
{
    __shared__ float wl[NEXP * HIDDEN];   // [e][h], 32 KB
    __shared__ float psl[4][NEXP];
    int tid = threadIdx.x;

    for (int i = tid; i < HIDDEN * NEXP / 4; i += 256) {
        float4 v = *(const float4*)(wr + i * 4);
        int m = i * 4, h = m >> 3, e = m & 7;
        wl[(e + 0) * HIDDEN + h] = v.x;
        wl[(e + 1) * HIDDEN + h] = v.y;
        wl[(e + 2) * HIDDEN + h] = v.z;
        wl[(e + 3) * HIDDEN + h] = v.w;
    }
    __syncthreads();

    int lane = tid & 63, wave = tid >> 6;
    int tok = blockIdx.x * 4 + wave;
    const float* xr = x + (size_t)tok * HIDDEN;

    float xv[16];
#pragma unroll
    for (int j = 0; j < 16; j++) xv[j] = xr[lane + 64 * j];

    bf16_t* xbr = xbf + (size_t)tok * HIDDEN;
#pragma unroll
    for (int j = 0; j < 16; j++) xbr[lane + 64 * j] = (bf16_t)xv[j];

    double acc[NEXP];
#pragma unroll
    for (int e = 0; e < NEXP; e++) acc[e] = 0.0;
#pragma unroll
    for (int j = 0; j < 16; j++) {
        int h = lane + 64 * j;
#pragma unroll
        for (int e = 0; e < NEXP; e++)
            acc[e] += (double)xv[j] * (double)wl[e * HIDDEN + h];
    }
#pragma unroll
    for (int e = 0; e < NEXP; e++) {
        double v = acc[e];
#pragma unroll
        for (int off = 32; off > 0; off >>= 1) v += __shfl_down(v, off);
        acc[e] = v;
    }
    if (lane == 0) {
        int e0 = 0;
#pragma unroll
        for (int e = 1; e < NEXP; e++) if (acc[e] > acc[e0]) e0 = e;
        int e1 = (e0 == 0) ? 1 : 0;
#pragma unroll
        for (int e = 0; e < NEXP; e++) if (e != e0 && acc[e] > acc[e1]) e1 = e;
        double w0 = 1.0 / (1.0 + exp(acc[e1] - acc[e0]));
        top_e[tok * 2 + 0] = e0;
        top_e[tok * 2 + 1] = e1;
        top_w[tok * 2 + 0] = (float)w0;
        top_w[tok * 2 + 1] = (float)(1.0 - w0);
        float mx = (float)acc[0];
#pragma unroll
        for (int e = 1; e < NEXP; e++) mx = fmaxf(mx, (float)acc[e]);
        float p[NEXP], s = 0.f;
#pragma unroll
        for (int e = 0; e < NEXP; e++) { p[e] = __expf((float)acc[e] - mx); s += p[e]; }
#pragma unroll
        for (int e = 0; e < NEXP; e++) psl[wave][e] = p[e] / s;
    }
    __syncthreads();
    if (tid < NEXP)
        psums[blockIdx.x * NEXP + tid] =
            psl[0][tid] + psl[1][tid] + psl[2][tid] + psl[3][tid];
}

// ------- Single-block: histogram + segments + aux + deterministic scatter -----
__global__ __launch_bounds__(256) void setup_scatter_kernel(
    const int* __restrict__ top_e, const float* __restrict__ psums, int nblk,
    int* __restrict__ hdr, int* __restrict__ row_tok, int* __restrict__ row_of,
    float* __restrict__ aux_out, int n)
{
    __shared__ int wcnt[4][16];
    __shared__ int sc1[NEXP], sc2[NEXP], segb[NEXP], segc[NEXP], cur[NEXP];
    __shared__ int woff[4][16];
    __shared__ float pred[NEXP];

    int tid = threadIdx.x, lane = tid & 63, wave = tid >> 6;
    if (tid < NEXP) pred[tid] = 0.f;

    int c1[NEXP] = {}, c2[NEXP] = {};
    for (int base = 0; base < n; base += 256) {
        int t = base + tid;
        int e0 = top_e[t * 2 + 0];
        int e1 = top_e[t * 2 + 1];
#pragma unroll
        for (int e = 0; e < NEXP; e++) {
            unsigned long long m0 = __ballot(e0 == e);
            unsigned long long m1 = __ballot(e1 == e);
            if (lane == 0) {
                c1[e] += __popcll(m0);
                c2[e] += __popcll(m0) + __popcll(m1);
            }
        }
    }
    if (lane == 0) {
#pragma unroll
        for (int e = 0; e < NEXP; e++) {
            wcnt[wave][e] = c2[e];
            wcnt[wave][8 + e] = c1[e];
        }
    }
    __syncthreads();
    if (tid < 16) {
        int s = wcnt[0][tid] + wcnt[1][tid] + wcnt[2][tid] + wcnt[3][tid];
        if (tid < 8) sc2[tid] = s; else sc1[tid - 8] = s;
    }
    __syncthreads();
    if (tid == 0) {
        int off = 0;
#pragma unroll
        for (int e = 0; e < NEXP; e++) {
            segb[e] = off; cur[e] = off;
            int cap = (sc2[e] + BM - 1) / BM * BM;
            segc[e] = cap; off += cap;
            hdr[e] = sc2[e]; hdr[8 + e] = sc1[e];
            hdr[24 + e] = segb[e]; hdr[32 + e] = cap;
        }
    }
    {
        float ps = 0.f;
        int e = tid & 7;
        for (int i = tid >> 3; i < nblk; i += 32) ps += psums[i * NEXP + e];
        ps += __shfl_down(ps, 32);
        ps += __shfl_down(ps, 16);
        ps += __shfl_down(ps, 8);
        if (lane < 8) atomicAdd(&pred[lane], ps);
    }
    __syncthreads();
    if (tid == 0) {
        double aux = 0.0;
#pragma unroll
        for (int e = 0; e < NEXP; e++)
            aux += ((double)sc1[e] / n) * ((double)pred[e] / n);
        *aux_out = (float)(aux * NEXP);
    }
#pragma unroll
    for (int e = 0; e < NEXP; e++)
        for (int r = sc2[e] + tid; r < segc[e]; r += 256)
            row_tok[segb[e] + r] = -1;
    __syncthreads();

    for (int base = 0; base < n; base += 256) {
        int t = base + tid;
        int e0 = top_e[t * 2 + 0];
        int e1 = top_e[t * 2 + 1];
        unsigned long long below = (lane == 63) ? ~0ull >> 1 : (1ull << lane) - 1;
        int r0 = 0, r1 = 0;
#pragma unroll
        for (int e = 0; e < NEXP; e++) {
            unsigned long long m0 = __ballot(e0 == e);
            unsigned long long m1 = __ballot(e1 == e);
            if (e0 == e) r0 = __popcll(m0 & below);
            if (e1 == e) r1 = __popcll(m1 & below);
            if (lane == 0) {
                woff[wave][e] = __popcll(m0);
                woff[wave][8 + e] = __popcll(m1);
            }
        }
        __syncthreads();
        int pre0 = 0, tot0_e1 = 0, pre1 = 0;
#pragma unroll
        for (int w = 0; w < 4; w++) {
            if (w < wave) pre0 += woff[w][e0];
            tot0_e1 += woff[w][e1];
            if (w < wave) pre1 += woff[w][8 + e1];
        }
        int row0 = cur[e0] + pre0 + r0;
        int row1 = cur[e1] + tot0_e1 + pre1 + r1;
        row_tok[row0] = t;
        row_tok[row1] = t;
        row_of[t * 2 + 0] = row0;
        row_of[t * 2 + 1] = row1;
        __syncthreads();
        if (tid < 8)
            cur[tid] += woff[0][tid] + woff[1][tid] + woff[2][tid] + woff[3][tid]
                      + woff[0][8 + tid] + woff[1][8 + tid] + woff[2][8 + tid]
                      + woff[3][8 + tid];
        __syncthreads();
    }
}

// ------- per-expert transpose-convert [R][C]f32 -> [C][R]bf16, 64x64 tiles ----
__global__ __launch_bounds__(256) void transpose_cvt_kernel(
    const float* __restrict__ src, bf16_t* __restrict__ dst, int R, int C)
{
    __shared__ float tile[64][65];
    int e = blockIdx.z;
    int r0 = blockIdx.y * 64, c0 = blockIdx.x * 64;
    int tid = threadIdx.x;

    int r = tid >> 4;              // 0..15
    int cq = (tid & 15) * 4;       // 0..60
    const float* s = src + ((size_t)e * R + r0 + r) * C + c0 + cq;
#pragma unroll
    for (int j = 0; j < 4; j++) {
        float4 v = *(const float4*)(s + (size_t)j * 16 * C);
        tile[r + j * 16][cq + 0] = v.x;
        tile[r + j * 16][cq + 1] = v.y;
        tile[r + j * 16][cq + 2] = v.z;
        tile[r + j * 16][cq + 3] = v.w;
    }
    __syncthreads();

    int c = tid >> 2;              // 0..63
    int rq = (tid & 3) * 16;       // 0,16,32,48
    bf16_t* d = dst + ((size_t)e * C + c0 + c) * R + r0 + rq;
    bf16x8 o0, o1;
#pragma unroll
    for (int j = 0; j < 8; j++) o0[j] = (bf16_t)tile[rq + j][c];
#pragma unroll
    for (int j = 0; j < 8; j++) o1[j] = (bf16_t)tile[rq + 8 + j][c];
    *(bf16x8*)(d + 0) = o0;
    *(bf16x8*)(d + 8) = o1;
}

// ---------------- expert lookup ----------------------------------------------
__device__ __forceinline__ int tile_expert(const int* hdr, int row0)
{
    int e = -1;
#pragma unroll
    for (int i = 0; i < NEXP; i++) {
        int sb = hdr[24 + i];
        if (row0 >= sb && row0 < sb + hdr[32 + i]) e = i;
    }
    if (e >= 0 && row0 - hdr[24 + e] >= hdr[e]) e = -1;
    return e;
}

// ---------------- GEMM1: Hbuf = silu(X[rows] @ W1[e]) bf16 MFMA ---------------
__global__ __launch_bounds__(256) void gemm1_kernel(
    const bf16_t* __restrict__ xbf, const bf16_t* __restrict__ w1t,
    const int* __restrict__ hdr, const int* __restrict__ row_tok,
    bf16_t* __restrict__ Hbuf)
{
    __shared__ __align__(16) bf16_t As[BM * BK];
    __shared__ __align__(16) bf16_t Bs[BN * BK];

    int row0 = blockIdx.x * BM;
    int e = tile_expert(hdr, row0);
    if (e < 0) return;
    int n0 = blockIdx.y * BN;
    int tid = threadIdx.x;

    int ar0 = tid >> 2, as0 = tid & 3, ak0 = as0 ^ swz(ar0);
    int ar1 = ar0 + 64, ak1 = as0 ^ swz(ar1);
    int t0 = row_tok[row0 + ar0]; if (t0 < 0) t0 = 0;
    int t1 = row_tok[row0 + ar1]; if (t1 < 0) t1 = 0;
    const bf16_t* ag0 = xbf + (size_t)t0 * HIDDEN + ak0 * 8;
    const bf16_t* ag1 = xbf + (size_t)t1 * HIDDEN + ak1 * 8;
    bf16_t* al0 = As + tid * 8;
    bf16_t* al1 = As + (tid + 256) * 8;

    const bf16_t* wb = w1t + (size_t)e * HIDDEN * INTER;
    const bf16_t* bg0 = wb + (size_t)(n0 + ar0) * HIDDEN + ak0 * 8;
    const bf16_t* bg1 = wb + (size_t)(n0 + ar1) * HIDDEN + ak1 * 8;
    bf16_t* bl0 = Bs + tid * 8;
    bf16_t* bl1 = Bs + (tid + 256) * 8;

    int wave = tid >> 6, lane = tid & 63;
    int wm = (wave >> 1) * 64, wn = (wave & 1) * 64;
    int lrow = lane & 15, q = lane >> 4;

    int aoff[4], boff[4];
#pragma unroll
    for (int i = 0; i < 4; i++) {
        int r = wm + i * 16 + lrow;
        aoff[i] = r * BK + (q ^ swz(r)) * 8;
        int s = wn + i * 16 + lrow;
        boff[i] = s * BK + (q ^ swz(s)) * 8;
    }

    f32x4 acc[4][4] = {};

    for (int k0 = 0; k0 < HIDDEN; k0 += BK) {
        async_cp16(ag0 + k0, al0);
        async_cp16(ag1 + k0, al1);
        async_cp16(bg0 + k0, bl0);
        async_cp16(bg1 + k0, bl1);
        __syncthreads();
        bf16x8 af[4], bfr[4];
#pragma unroll
        for (int i = 0; i < 4; i++) {
            af[i]  = *(const bf16x8*)(As + aoff[i]);
            bfr[i] = *(const bf16x8*)(Bs + boff[i]);
        }
#pragma unroll
        for (int mi = 0; mi < 4; mi++)
#pragma unroll
            for (int nj = 0; nj < 4; nj++)
                acc[mi][nj] = __builtin_amdgcn_mfma_f32_16x16x32_bf16(
                    bfr[nj], af[mi], acc[mi][nj], 0, 0, 0);
        __syncthreads();
    }

#pragma unroll
    for (int mi = 0; mi < 4; mi++) {
        size_t rb = (size_t)(row0 + wm + mi * 16 + lrow) * INTER + n0 + wn + q * 4;
#pragma unroll
        for (int nj = 0; nj < 4; nj++) {
            f32x4 v = acc[mi][nj];
            bf16x4 o = {
                (bf16_t)(v.x * __builtin_amdgcn_rcpf(1.f + __expf(-v.x))),
                (bf16_t)(v.y * __builtin_amdgcn_rcpf(1.f + __expf(-v.y))),
                (bf16_t)(v.z * __builtin_amdgcn_rcpf(1.f + __expf(-v.z))),
                (bf16_t)(v.w * __builtin_amdgcn_rcpf(1.f + __expf(-v.w))) };
            *(bf16x4*)(Hbuf + rb + nj * 16) = o;
        }
    }
}

// ---------------- GEMM2: Obuf = Hbuf[rows] @ W2[e] ----------------------------
__global__ __launch_bounds__(256) void gemm2_kernel(
    const bf16_t* __restrict__ Hbuf, const bf16_t* __restrict__ w2t,
    const int* __restrict__ hdr, bf16_t* __restrict__ Obuf)
{
    __shared__ __align__(16) bf16_t As[BM * BK];
    __shared__ __align__(16) bf16_t Bs[BN * BK];

    int row0 = blockIdx.x * BM;
    int e = tile_expert(hdr, row0);
    if (e < 0) return;
    int n0 = blockIdx.y * BN;
    int tid = threadIdx.x;

    int ar0 = tid >> 2, as0 = tid & 3, ak0 = as0 ^ swz(ar0);
    int ar1 = ar0 + 64, ak1 = as0 ^ swz(ar1);
    const bf16_t* ag0 = Hbuf + (size_t)(row0 + ar0) * INTER + ak0 * 8;
    const bf16_t* ag1 = Hbuf + (size_t)(row0 + ar1) * INTER + ak1 * 8;
    bf16_t* al0 = As + tid * 8;
    bf16_t* al1 = As + (tid + 256) * 8;

    const bf16_t* wb = w2t + (size_t)e * HIDDEN * INTER;
    const bf16_t* bg0 = wb + (size_t)(n0 + ar0) * INTER + ak0 * 8;
    const bf16_t* bg1 = wb + (size_t)(n0 + ar1) * INTER + ak1 * 8;
    bf16_t* bl0 = Bs + tid * 8;
    bf16_t* bl1 = Bs + (tid + 256) * 8;

    int wave = tid >> 6, lane = tid & 63;
    int wm = (wave >> 1) * 64, wn = (wave & 1) * 64;
    int lrow = lane & 15, q = lane >> 4;

    int aoff[4], boff[4];
#pragma unroll
    for (int i = 0; i < 4; i++) {
        int r = wm + i * 16 + lrow;
        aoff[i] = r * BK + (q ^ swz(r)) * 8;
        int s = wn + i * 16 + lrow;
        boff[i] = s * BK + (q ^ swz(s)) * 8;
    }

    f32x4 acc[4][4] = {};

    for (int k0 = 0; k0 < INTER; k0 += BK) {
        async_cp16(ag0 + k0, al0);
        async_cp16(ag1 + k0, al1);
        async_cp16(bg0 + k0, bl0);
        async_cp16(bg1 + k0, bl1);
        __syncthreads();
        bf16x8 af[4], bfr[4];
#pragma unroll
        for (int i = 0; i < 4; i++) {
            af[i]  = *(const bf16x8*)(As + aoff[i]);
            bfr[i] = *(const bf16x8*)(Bs + boff[i]);
        }
#pragma unroll
        for (int mi = 0; mi < 4; mi++)
#pragma unroll
            for (int nj = 0; nj < 4; nj++)
                acc[mi][nj] = __builtin_amdgcn_mfma_f32_16x16x32_bf16(
                    bfr[nj], af[mi], acc[mi][nj], 0, 0, 0);
        __syncthreads();
    }

#pragma unroll
    for (int mi = 0; mi < 4; mi++) {
        size_t rb = (size_t)(row0 + wm + mi * 16 + lrow) * HIDDEN + n0 + wn + q * 4;
#pragma unroll
        for (int nj = 0; nj < 4; nj++) {
            f32x4 v = acc[mi][nj];
            bf16x4 o = { (bf16_t)v.x, (bf16_t)v.y, (bf16_t)v.z, (bf16_t)v.w };
            *(bf16x4*)(Obuf + rb + nj * 16) = o;
        }
    }
}

// ---------------- Combine: out[t] = w0*Obuf[r0] + w1*Obuf[r1] -----------------
__global__ __launch_bounds__(256) void combine_kernel(
    const bf16_t* __restrict__ Obuf, const int* __restrict__ row_of,
    const float* __restrict__ top_w, float* __restrict__ out)
{
    int t = blockIdx.x;
    int r0 = row_of[t * 2 + 0], r1 = row_of[t * 2 + 1];
    float w0 = top_w[t * 2 + 0], w1 = top_w[t * 2 + 1];
    int c = threadIdx.x * 4;
    bf16x4 a = *(const bf16x4*)(Obuf + (size_t)r0 * HIDDEN + c);
    bf16x4 b = *(const bf16x4*)(Obuf + (size_t)r1 * HIDDEN + c);
    float4 o;
    o.x = w0 * (float)a.x + w1 * (float)b.x;
    o.y = w0 * (float)a.y + w1 * (float)b.y;
    o.z = w0 * (float)a.z + w1 * (float)b.z;
    o.w = w0 * (float)a.w + w1 * (float)b.w;
    *(float4*)(out + (size_t)t * HIDDEN + c) = o;
}

// ---------------- Launch ------------------------------------------------------
extern "C" void kernel_launch(void* const* d_in, const int* in_sizes, int n_in,
                              void* d_out, int out_size, void* d_ws, size_t ws_size,
                              hipStream_t stream)
{
    const float* x  = (const float*)d_in[0];
    const float* wr = (const float*)d_in[1];
    const float* w1 = (const float*)d_in[2];
    const float* w2 = (const float*)d_in[3];
    float* out = (float*)d_out;

    int n = in_sizes[0] / HIDDEN;                                  // 8192
    int nblk = n / 4;                                              // 2048
    int rowcap = ((2 * n + NEXP * (BM - 1)) + BM - 1) / BM * BM;   // 17408

    char* ws = (char*)d_ws;
    int* hdr = (int*)ws;
    size_t off = 512;
    int* row_tok = (int*)(ws + off); off += (size_t)rowcap * 4;
    int* row_of  = (int*)(ws + off); off += (size_t)n * 2 * 4;
    int* top_e   = (int*)(ws + off); off += (size_t)n * 2 * 4;
    float* top_w = (float*)(ws + off); off += (size_t)n * 2 * 4;
    float* psums = (float*)(ws + off); off += (size_t)nblk * NEXP * 4;
    off = (off + 255) & ~(size_t)255;
    size_t xbf_off = off;
    bf16_t* xbf = (bf16_t*)(ws + off);  off += (size_t)n * HIDDEN * 2;
    bf16_t* w1t = (bf16_t*)(ws + off);  off += (size_t)NEXP * HIDDEN * INTER * 2;
    bf16_t* w2t = (bf16_t*)(ws + off);  off += (size_t)NEXP * HIDDEN * INTER * 2;
    bf16_t* Hbuf = (bf16_t*)(ws + off); off += (size_t)rowcap * INTER * 2;
    bf16_t* Obuf = (bf16_t*)(ws + xbf_off);   // aliases xbf+w1t (dead after gemm1)

    router_kernel<<<nblk, 256, 0, stream>>>(x, wr, top_e, top_w, psums, xbf);
    transpose_cvt_kernel<<<dim3(INTER / 64, HIDDEN / 64, NEXP), 256, 0, stream>>>(
        w1, w1t, HIDDEN, INTER);
    transpose_cvt_kernel<<<dim3(HIDDEN / 64, INTER / 64, NEXP), 256, 0, stream>>>(
        w2, w2t, INTER, HIDDEN);
    setup_scatter_kernel<<<1, 256, 0, stream>>>(top_e, psums, nblk, hdr,
                                                row_tok, row_of,
                                                out + (out_size - 1), n);

    dim3 g1(rowcap / BM, INTER / BN);
    gemm1_kernel<<<g1, 256, 0, stream>>>(xbf, w1t, hdr, row_tok, Hbuf);
    dim3 g2(rowcap / BM, HIDDEN / BN);
    gemm2_kernel<<<g2, 256, 0, stream>>>(Hbuf, w2t, hdr, Obuf);
    combine_kernel<<<n, 256, 0, stream>>>(Obuf, row_of, top_w, out);
}